// Round 8
// baseline (360.468 us; speedup 1.0000x reference)
//
#include <hip/hip_runtime.h>
#include <cmath>
#include <cstdint>

typedef __bf16 bf16;
typedef __bf16 bf16x8 __attribute__((ext_vector_type(8)));
typedef __bf16 bf16x4 __attribute__((ext_vector_type(4)));
typedef float  f32x4  __attribute__((ext_vector_type(4)));

#define M_TOK 8192
#define SCALE_ 0.10206207261596575f   // 96^-0.5
#define SB0 __builtin_amdgcn_sched_barrier(0)

__device__ __forceinline__ void gld_lds16(const void* g, void* l) {
  __builtin_amdgcn_global_load_lds(
      (__attribute__((address_space(1))) void*)(uintptr_t)g,
      (__attribute__((address_space(3))) void*)(uintptr_t)l,
      16, 0, 0);
}

// tanh-approx GELU (max |err| vs exact ~3e-3); tanh via v_exp_f32
__device__ __forceinline__ float gelu_f(float x) {
  float u = x * (0.7978845608f + 0.0356774081f * x * x);
  float t = 1.0f - 2.0f / (__expf(2.0f * u) + 1.0f);
  return 0.5f * x * (1.0f + t);
}

// ------- weight -> MFMA-fragment layout (B-operand order), all 4 weights -----
__global__ __launch_bounds__(256) void make_frags_kernel(
    const float* __restrict__ w_qkv, const float* __restrict__ w_o,
    const float* __restrict__ w1, const float* __restrict__ w2,
    bf16* __restrict__ fqkv, bf16* __restrict__ fwo, bf16* __restrict__ fw1,
    bf16* __restrict__ fw2) {
  int chunk = blockIdx.x * 4 + (threadIdx.x >> 6);
  int lane = threadIdx.x & 63;
  const float* src;
  bf16* dst;
  int K, N, base;
  if (chunk < 3456) {
    src = w_qkv; dst = fqkv; K = 768; N = 2304; base = 0;
  } else if (chunk < 4608) {
    src = w_o; dst = fwo; K = 768; N = 768; base = 3456;
  } else if (chunk < 9216) {
    src = w1; dst = fw1; K = 768; N = 3072; base = 4608;
  } else {
    src = w2; dst = fw2; K = 3072; N = 768; base = 9216;
  }
  int lid = chunk - base;
  int kc = K / 32;
  int n16 = lid / kc, c = lid - n16 * kc;
  int lr = lane & 15, qd = lane >> 4;
  int n = n16 * 16 + lr;
  int k0 = c * 32 + qd * 8;
  bf16x8 v;
#pragma unroll
  for (int e = 0; e < 8; e++) v[e] = (bf16)src[(size_t)(k0 + e) * N + n];
  *(bf16x8*)&dst[(size_t)lid * 512 + lane * 8] = v;
}

// ---------------- layernorm (f32 in -> bf16 out), one wave per row ------------
__global__ __launch_bounds__(256) void ln_kernel(
    const float* __restrict__ x, const float* __restrict__ g,
    const float* __restrict__ b, bf16* __restrict__ ob) {
  int w = threadIdx.x >> 6, lane = threadIdx.x & 63;
  size_t row = (size_t)blockIdx.x * 4 + w;
  const float* xr = x + row * 768;
  float4 v[3];
  float s = 0.f, sq = 0.f;
#pragma unroll
  for (int k = 0; k < 3; k++) {
    v[k] = *(const float4*)(xr + (k * 64 + lane) * 4);
    s += v[k].x + v[k].y + v[k].z + v[k].w;
    sq += v[k].x * v[k].x + v[k].y * v[k].y + v[k].z * v[k].z + v[k].w * v[k].w;
  }
#pragma unroll
  for (int off = 32; off >= 1; off >>= 1) {
    s += __shfl_xor(s, off);
    sq += __shfl_xor(sq, off);
  }
  float mean = s * (1.f / 768.f);
  float rstd = rsqrtf(sq * (1.f / 768.f) - mean * mean + 1e-5f);
#pragma unroll
  for (int k = 0; k < 3; k++) {
    int c = (k * 64 + lane) * 4;
    float4 gg = *(const float4*)(g + c);
    float4 bb = *(const float4*)(b + c);
    bf16x4 pk = {(bf16)((v[k].x - mean) * rstd * gg.x + bb.x),
                 (bf16)((v[k].y - mean) * rstd * gg.y + bb.y),
                 (bf16)((v[k].z - mean) * rstd * gg.z + bb.z),
                 (bf16)((v[k].w - mean) * rstd * gg.w + bb.w)};
    *(bf16x4*)(ob + row * 768 + c) = pk;
  }
}

// ------- ln2_reduce: t = p0+p1+b_o+x(resid f32); x2=t (bf16); h2 = LN(t) bf16 -
__global__ __launch_bounds__(256) void ln2_reduce_kernel(
    const bf16* __restrict__ p, const float* __restrict__ bo,
    const float* __restrict__ xres, const float* __restrict__ g,
    const float* __restrict__ b, bf16* __restrict__ x2,
    bf16* __restrict__ h2) {
  int w = threadIdx.x >> 6, lane = threadIdx.x & 63;
  size_t row = (size_t)blockIdx.x * 4 + w;
  const bf16* p0 = p + row * 768;
  const bf16* p1 = p0 + (size_t)M_TOK * 768;
  const float* xr = xres + row * 768;
  float4 v[3];
  float s = 0.f, sq = 0.f;
#pragma unroll
  for (int k = 0; k < 3; k++) {
    int c = (k * 64 + lane) * 4;
    bf16x4 a0 = *(const bf16x4*)(p0 + c);
    bf16x4 a1 = *(const bf16x4*)(p1 + c);
    float4 bb = *(const float4*)(bo + c);
    float4 rr = *(const float4*)(xr + c);
    v[k].x = (float)a0[0] + (float)a1[0] + bb.x + rr.x;
    v[k].y = (float)a0[1] + (float)a1[1] + bb.y + rr.y;
    v[k].z = (float)a0[2] + (float)a1[2] + bb.z + rr.z;
    v[k].w = (float)a0[3] + (float)a1[3] + bb.w + rr.w;
    bf16x4 xo = {(bf16)v[k].x, (bf16)v[k].y, (bf16)v[k].z, (bf16)v[k].w};
    *(bf16x4*)(x2 + row * 768 + c) = xo;
    s += v[k].x + v[k].y + v[k].z + v[k].w;
    sq += v[k].x * v[k].x + v[k].y * v[k].y + v[k].z * v[k].z + v[k].w * v[k].w;
  }
#pragma unroll
  for (int off = 32; off >= 1; off >>= 1) {
    s += __shfl_xor(s, off);
    sq += __shfl_xor(sq, off);
  }
  float mean = s * (1.f / 768.f);
  float rstd = rsqrtf(sq * (1.f / 768.f) - mean * mean + 1e-5f);
#pragma unroll
  for (int k = 0; k < 3; k++) {
    int c = (k * 64 + lane) * 4;
    float4 gg = *(const float4*)(g + c);
    float4 bb = *(const float4*)(b + c);
    bf16x4 pk = {(bf16)((v[k].x - mean) * rstd * gg.x + bb.x),
                 (bf16)((v[k].y - mean) * rstd * gg.y + bb.y),
                 (bf16)((v[k].z - mean) * rstd * gg.z + bb.z),
                 (bf16)((v[k].w - mean) * rstd * gg.w + bb.w)};
    *(bf16x4*)(h2 + row * 768 + c) = pk;
  }
}

// ------- ln3_reduce: t = gelu(p0+p1+b2)+x2(bf16); out = LN(t) f32 -------------
__global__ __launch_bounds__(256) void ln3_reduce_kernel(
    const bf16* __restrict__ p, const float* __restrict__ b2,
    const bf16* __restrict__ x2, const float* __restrict__ g,
    const float* __restrict__ b, float* __restrict__ out) {
  int w = threadIdx.x >> 6, lane = threadIdx.x & 63;
  size_t row = (size_t)blockIdx.x * 4 + w;
  const bf16* p0 = p + row * 768;
  const bf16* p1 = p0 + (size_t)M_TOK * 768;
  const bf16* xr = x2 + row * 768;
  float4 v[3];
  float s = 0.f, sq = 0.f;
#pragma unroll
  for (int k = 0; k < 3; k++) {
    int c = (k * 64 + lane) * 4;
    bf16x4 a0 = *(const bf16x4*)(p0 + c);
    bf16x4 a1 = *(const bf16x4*)(p1 + c);
    float4 bb = *(const float4*)(b2 + c);
    bf16x4 rr = *(const bf16x4*)(xr + c);
    v[k].x = gelu_f((float)a0[0] + (float)a1[0] + bb.x) + (float)rr[0];
    v[k].y = gelu_f((float)a0[1] + (float)a1[1] + bb.y) + (float)rr[1];
    v[k].z = gelu_f((float)a0[2] + (float)a1[2] + bb.z) + (float)rr[2];
    v[k].w = gelu_f((float)a0[3] + (float)a1[3] + bb.w) + (float)rr[3];
    s += v[k].x + v[k].y + v[k].z + v[k].w;
    sq += v[k].x * v[k].x + v[k].y * v[k].y + v[k].z * v[k].z + v[k].w * v[k].w;
  }
#pragma unroll
  for (int off = 32; off >= 1; off >>= 1) {
    s += __shfl_xor(s, off);
    sq += __shfl_xor(sq, off);
  }
  float mean = s * (1.f / 768.f);
  float rstd = rsqrtf(sq * (1.f / 768.f) - mean * mean + 1e-5f);
#pragma unroll
  for (int k = 0; k < 3; k++) {
    int c = (k * 64 + lane) * 4;
    float4 gg = *(const float4*)(g + c);
    float4 bb = *(const float4*)(b + c);
    float4 ov = {(v[k].x - mean) * rstd * gg.x + bb.x,
                 (v[k].y - mean) * rstd * gg.y + bb.y,
                 (v[k].z - mean) * rstd * gg.z + bb.z,
                 (v[k].w - mean) * rstd * gg.w + bb.w};
    *(float4*)(out + row * 768 + c) = ov;
  }
}

// ---------------- GEMM 256x256, faithful m201 8-phase port --------------------
// ROUND-8: the 128^2 structure class is plateaued at 26-30% MfmaUtil across 4
// schedule variants (R3/R5/R6/R7). Port the verified 256^2 8-phase template
// correctly this time. R4's failure causes fixed: (a) vmcnt(2)->vmcnt(6)
// counted gates ONLY at phases 4/8 (3 half-tiles in flight, never drained);
// (b) A split by K-CHUNK (not M-half) so a legal 1-half-per-phase staging
// stream exists. Geometry: BM=BN=256, BK=64, 8 waves (2M x 4N), per-wave
// 128x64 (acc 8x4), 2 x 64KB LDS buffers [A_k0|A_k1|B_k0|B_k1] x 16KB.
// Phase p of tile T(buf b): {4-8 ds_read ; stage 1 half (2 gld_lds) ;
// barrier ; lgkm(0) ; setprio(1) 16 MFMA setprio(0) ; [gate] ; barrier}.
// Stage stream (iter = tiles T,T+1): ph1:A_k1(T+1)->b1, ph2:B_k0(T+2)->b0,
// ph3:A_k0(T+2), ph4:B_k1(T+2)+GATE6, ph5:A_k1(T+2), ph6:B_k0(T+3)->b1,
// ph7:A_k0(T+3), ph8:B_k1(T+3)+GATE6. Every slot's last read (lgkm'd +
// barrier'd) precedes its overwrite; every tile fully staged >=1 gate before
// first read. A swizzle = R5's measured-0-conflict pattern (chunk ^= (row>>1)&3,
// pre-swizzled source + same XOR on read); B fragment-linear.
// K order per output element unchanged (kc0 then kc1 per tile, tiles in order).
template <int EPI, int LDA, int KTOT, int KSL, int NN>
__global__ __launch_bounds__(512, 1) void gemm256_kernel(
    const bf16* __restrict__ A, const bf16* __restrict__ Bf,
    const float* __restrict__ bias, bf16* __restrict__ outb,
    bf16* __restrict__ qo, bf16* __restrict__ ko, bf16* __restrict__ vto) {
  constexpr int KCg = KTOT / 32;   // B frag chunks per n16 row
  constexpr int NT = KSL / 64;     // K-tiles: 12 (qkv/w1) / 24 (w2) — even
  constexpr int NI = NT / 2;
  __shared__ __align__(16) bf16 smem[2][32768];  // [A_k0|A_k1|B_k0|B_k1]x8192
  int tid = threadIdx.x;
  int w = tid >> 6, l = tid & 63;
  int qd = l >> 4, lr = l & 15;
  int bm0 = blockIdx.x * 256, bn0 = blockIdx.y * 256;
  int kb = blockIdx.z * KSL;
  int wm = (w >> 2) * 128;   // wave M group (rows wm..wm+127)
  int wn = (w & 3) * 64;     // wave N group
  int wnl = (w & 3) * 4;     // first n16 frag

  // staging sources (per-lane; LDS dest = wave-uniform + lane*16B linear)
  // A: thread covers row w*32 + g*16 + (l>>2), dest 16B-chunk (l&3) of the
  //    32-elem k-chunk; source chunk pre-swizzled by (row>>1)&3 == (l>>3)&3.
  const bf16* pA = A + (size_t)(bm0 + w * 32 + (l >> 2)) * LDA + kb +
                   (((l & 3) ^ ((l >> 3) & 3)) * 8);
  // B: wave w stages n16 groups {2w, 2w+1}
  const bf16* pB =
      Bf + ((size_t)((bn0 >> 4) + 2 * w) * KCg + (kb >> 5)) * 512 + l * 8;

  auto STG_A = [&](int t, int kc, bf16* buf) {  // one A k-half: 2 glds
    const bf16* s = pA + t * 64 + kc * 32;
    char* d = (char*)buf + kc * 16384 + w * 2048;
    gld_lds16(s, d);
    gld_lds16(s + (size_t)16 * LDA, d + 1024);
  };
  auto STG_B = [&](int t, int kc, bf16* buf) {  // one B k-half: 2 glds
    const bf16* s = pB + (size_t)(t * 2 + kc) * 512;
    char* d = (char*)buf + 32768 + kc * 16384 + w * 2048;
    gld_lds16(s, d);
    gld_lds16(s + (size_t)KCg * 512, d + 1024);
  };
  auto LD_A4 = [&](const bf16* buf, int kc, int i0, bf16x8* af) {
#pragma unroll
    for (int i = 0; i < 4; ++i) {
      int r = wm + (i0 + i) * 16 + lr;
      af[i] = *(const bf16x8*)(buf + kc * 8192 + r * 32 +
                               ((qd ^ ((lr >> 1) & 3)) * 8));
    }
  };
  auto LD_B4 = [&](const bf16* buf, int kc, bf16x8* bv) {
#pragma unroll
    for (int j = 0; j < 4; ++j)
      bv[j] = *(const bf16x8*)(buf + 16384 + kc * 8192 + (wnl + j) * 512 +
                               l * 8);
  };

  f32x4 acc[8][4] = {};
  auto MM = [&](bf16x8* af, bf16x8* bv, int i0) {
#pragma unroll
    for (int i = 0; i < 4; ++i)
#pragma unroll
      for (int j = 0; j < 4; ++j)
        acc[i0 + i][j] = __builtin_amdgcn_mfma_f32_16x16x32_bf16(
            af[i], bv[j], acc[i0 + i][j], 0, 0, 0);
  };

  bf16* b0 = smem[0];
  bf16* b1 = smem[1];

  // ---- prologue: T0 complete (8 glds) + T1 {B_k0,A_k0,B_k1} (6 glds) ----
  STG_B(0, 0, b0); STG_A(0, 0, b0); STG_B(0, 1, b0); STG_A(0, 1, b0);
  STG_B(1, 0, b1); STG_A(1, 0, b1); STG_B(1, 1, b1);
  asm volatile("s_waitcnt vmcnt(6)" ::: "memory");  // T0 landed
  SB0;
  __builtin_amdgcn_s_barrier();
  SB0;

  bf16x8 af[4], bv[4];

#pragma unroll 1
  for (int it = 0; it < NI; ++it) {
    const int T = 2 * it;
    const bool st = (it + 1 < NI);

    // ph1: T kc0 Mh0 | stage A_k1(T+1)->b1
    SB0; LD_B4(b0, 0, bv); LD_A4(b0, 0, 0, af); SB0;
    STG_A(T + 1, 1, b1);
    SB0; __builtin_amdgcn_s_barrier();
    asm volatile("s_waitcnt lgkmcnt(0)" ::: "memory"); SB0;
    __builtin_amdgcn_s_setprio(1); MM(af, bv, 0); __builtin_amdgcn_s_setprio(0);
    SB0; __builtin_amdgcn_s_barrier();

    // ph2: T kc0 Mh1 | stage B_k0(T+2)->b0
    SB0; LD_A4(b0, 0, 4, af); SB0;
    if (st) STG_B(T + 2, 0, b0);
    SB0; __builtin_amdgcn_s_barrier();
    asm volatile("s_waitcnt lgkmcnt(0)" ::: "memory"); SB0;
    __builtin_amdgcn_s_setprio(1); MM(af, bv, 4); __builtin_amdgcn_s_setprio(0);
    SB0; __builtin_amdgcn_s_barrier();

    // ph3: T kc1 Mh0 | stage A_k0(T+2)->b0
    SB0; LD_B4(b0, 1, bv); LD_A4(b0, 1, 0, af); SB0;
    if (st) STG_A(T + 2, 0, b0);
    SB0; __builtin_amdgcn_s_barrier();
    asm volatile("s_waitcnt lgkmcnt(0)" ::: "memory"); SB0;
    __builtin_amdgcn_s_setprio(1); MM(af, bv, 0); __builtin_amdgcn_s_setprio(0);
    SB0; __builtin_amdgcn_s_barrier();

    // ph4: T kc1 Mh1 | stage B_k1(T+2)->b0 | GATE: T+1 landed
    SB0; LD_A4(b0, 1, 4, af); SB0;
    if (st) STG_B(T + 2, 1, b0);
    SB0; __builtin_amdgcn_s_barrier();
    asm volatile("s_waitcnt lgkmcnt(0)" ::: "memory"); SB0;
    __builtin_amdgcn_s_setprio(1); MM(af, bv, 4); __builtin_amdgcn_s_setprio(0);
    SB0;
    if (st) asm volatile("s_waitcnt vmcnt(6)" ::: "memory");
    else    asm volatile("s_waitcnt vmcnt(0)" ::: "memory");
    SB0; __builtin_amdgcn_s_barrier();

    // ph5: T+1 kc0 Mh0 | stage A_k1(T+2)->b0
    SB0; LD_B4(b1, 0, bv); LD_A4(b1, 0, 0, af); SB0;
    if (st) STG_A(T + 2, 1, b0);
    SB0; __builtin_amdgcn_s_barrier();
    asm volatile("s_waitcnt lgkmcnt(0)" ::: "memory"); SB0;
    __builtin_amdgcn_s_setprio(1); MM(af, bv, 0); __builtin_amdgcn_s_setprio(0);
    SB0; __builtin_amdgcn_s_barrier();

    // ph6: T+1 kc0 Mh1 | stage B_k0(T+3)->b1
    SB0; LD_A4(b1, 0, 4, af); SB0;
    if (st) STG_B(T + 3, 0, b1);
    SB0; __builtin_amdgcn_s_barrier();
    asm volatile("s_waitcnt lgkmcnt(0)" ::: "memory"); SB0;
    __builtin_amdgcn_s_setprio(1); MM(af, bv, 4); __builtin_amdgcn_s_setprio(0);
    SB0; __builtin_amdgcn_s_barrier();

    // ph7: T+1 kc1 Mh0 | stage A_k0(T+3)->b1
    SB0; LD_B4(b1, 1, bv); LD_A4(b1, 1, 0, af); SB0;
    if (st) STG_A(T + 3, 0, b1);
    SB0; __builtin_amdgcn_s_barrier();
    asm volatile("s_waitcnt lgkmcnt(0)" ::: "memory"); SB0;
    __builtin_amdgcn_s_setprio(1); MM(af, bv, 0); __builtin_amdgcn_s_setprio(0);
    SB0; __builtin_amdgcn_s_barrier();

    // ph8: T+1 kc1 Mh1 | stage B_k1(T+3)->b1 | GATE: T+2 landed
    SB0; LD_A4(b1, 1, 4, af); SB0;
    if (st) STG_B(T + 3, 1, b1);
    SB0; __builtin_amdgcn_s_barrier();
    asm volatile("s_waitcnt lgkmcnt(0)" ::: "memory"); SB0;
    __builtin_amdgcn_s_setprio(1); MM(af, bv, 4); __builtin_amdgcn_s_setprio(0);
    SB0;
    if (st) {
      asm volatile("s_waitcnt vmcnt(6)" ::: "memory");
      SB0;
      __builtin_amdgcn_s_barrier();
    }
  }

  // ---- epilogue ----
  bf16* outbs = (EPI == 5) ? outb + (size_t)blockIdx.z * M_TOK * NN : outb;

#pragma unroll
  for (int i = 0; i < 8; i++) {
#pragma unroll
    for (int j = 0; j < 4; j++) {
      if (EPI == 4) {
        // fused qkv split (NN==2304). 16-col tiles never straddle head bounds.
        int colt = bn0 + wn + j * 16;
        int which = colt / 768;
        int rem = colt - which * 768;
        int h = rem / 96;
        int dhb = rem - h * 96;
        int row0 = bm0 + wm + i * 16 + qd * 4;
        int b = row0 >> 10, n0 = row0 & 1023;
        int bh = b * 8 + h;
        if (which == 2) {
          bf16x4 pk = {(bf16)acc[i][j][0], (bf16)acc[i][j][1],
                       (bf16)acc[i][j][2], (bf16)acc[i][j][3]};
          *(bf16x4*)(vto + ((size_t)(bh * 96 + dhb + lr)) * 1024 + n0) = pk;
        } else if (which == 0) {
          // q pre-scaled by 1/sqrt(dh) so attention skips the S-scale
#pragma unroll
          for (int r = 0; r < 4; r++)
            qo[((size_t)bh * 1024 + n0 + r) * 96 + dhb + lr] =
                (bf16)(acc[i][j][r] * SCALE_);
        } else {
#pragma unroll
          for (int r = 0; r < 4; r++)
            ko[((size_t)bh * 1024 + n0 + r) * 96 + dhb + lr] =
                (bf16)acc[i][j][r];
        }
      } else {
#pragma unroll
        for (int r = 0; r < 4; r++) {
          int row = bm0 + wm + i * 16 + qd * 4 + r;
          int col = bn0 + wn + j * 16 + lr;
          size_t o = (size_t)row * NN + col;
          float v = acc[i][j][r];
          if (EPI == 2) {
            outbs[o] = (bf16)gelu_f(v + bias[col]);
          } else {  // EPI == 5
            outbs[o] = (bf16)v;
          }
        }
      }
    }
  }
}

// ---------------- GEMM 128x128 (R7 best) — used for Wo only ------------------
template <int EPI, int LDA, int KTOT, int KSL, int NN>
__global__ __launch_bounds__(256, 3) void gemm128_kernel(
    const bf16* __restrict__ A, const bf16* __restrict__ Bf,
    const float* __restrict__ bias, bf16* __restrict__ outb,
    bf16* __restrict__ qo, bf16* __restrict__ ko, bf16* __restrict__ vto) {
  constexpr int KCg = KTOT / 32;
  constexpr int NT = KSL / 32;
  __shared__ __align__(16) bf16 smem[3][8192];
  int tid = threadIdx.x;
  int w = tid >> 6, l = tid & 63;
  int qd = l >> 4, lr = l & 15;
  int id2 = blockIdx.y * gridDim.x + blockIdx.x;
  int xcd = id2 & 7;
  int slot = id2 >> 3;
  int Mg = gridDim.x >> 3;
  int mt = xcd * Mg + (slot % Mg);
  int ntl = slot / Mg;
  int bm0 = mt * 128, bn0 = ntl * 128;
  int kb = blockIdx.z * KSL;
  int wm = (w >> 1) * 64, wn = (w & 1) * 64;
  int wnl = (w & 1) * 4;

  const bf16* pA = A + (size_t)(bm0 + w * 32 + (l >> 2)) * LDA + kb +
                   (((l & 3) ^ ((l >> 3) & 3)) * 8);
  const bf16* pB =
      Bf + ((size_t)((bn0 >> 4) + w * 2) * KCg + (kb >> 5)) * 512 + l * 8;

  auto STG = [&](int t, int b) {
    char* dA = (char*)smem[b] + w * 2048;
    char* dB = (char*)smem[b] + 8192 + w * 2048;
    gld_lds16(pA + t * 32, dA);
    gld_lds16(pA + t * 32 + (size_t)16 * LDA, dA + 1024);
    gld_lds16(pB + (size_t)t * 512, dB);
    gld_lds16(pB + (size_t)KCg * 512 + (size_t)t * 512, dB + 1024);
  };
  auto LDF = [&](int b, bf16x8* af, bf16x8* bv) {
    const bf16* Ab = smem[b];
    const bf16* Bb = smem[b] + 4096;
#pragma unroll
    for (int i = 0; i < 4; ++i) {
      int r = wm + i * 16 + lr;
      af[i] = *(const bf16x8*)(Ab + r * 32 + ((qd ^ ((lr >> 1) & 3)) * 8));
    }
#pragma unroll
    for (int j = 0; j < 4; ++j)
      bv[j] = *(const bf16x8*)(Bb + (wnl + j) * 512 + l * 8);
  };

  f32x4 acc[4][4] = {};

  STG(0, 0);
  STG(1, 1);
  asm volatile("s_waitcnt vmcnt(4)" ::: "memory");
  SB0;
  __builtin_amdgcn_s_barrier();

#pragma unroll 1
  for (int t3 = 0; t3 < NT; t3 += 3) {
#pragma unroll
    for (int u = 0; u < 3; ++u) {
      const int t = t3 + u;
      const bool st = (t + 2) < NT;
      if (st) STG(t + 2, (u + 2) % 3);
      SB0;
      bf16x8 af[4], bv[4];
      LDF(u, af, bv);
      asm volatile("s_waitcnt lgkmcnt(0)" ::: "memory");
      SB0;
      __builtin_amdgcn_s_setprio(1);
#pragma unroll
      for (int i = 0; i < 4; ++i)
#pragma unroll
        for (int j = 0; j < 4; ++j)
          acc[i][j] = __builtin_amdgcn_mfma_f32_16x16x32_bf16(
              af[i], bv[j], acc[i][j], 0, 0, 0);
      __builtin_amdgcn_s_setprio(0);
      if (t + 1 < NT) {
        if (st) asm volatile("s_waitcnt vmcnt(4)" ::: "memory");
        else    asm volatile("s_waitcnt vmcnt(0)" ::: "memory");
        SB0;
        __builtin_amdgcn_s_barrier();
      }
    }
  }

  bf16* outbs = (EPI == 5) ? outb + (size_t)blockIdx.z * M_TOK * NN : outb;

#pragma unroll
  for (int i = 0; i < 4; i++) {
#pragma unroll
    for (int j = 0; j < 4; j++) {
#pragma unroll
      for (int r = 0; r < 4; r++) {
        int row = bm0 + wm + i * 16 + qd * 4 + r;
        int col = bn0 + wn + j * 16 + lr;
        size_t o = (size_t)row * NN + col;
        float v = acc[i][j][r];
        if (EPI == 2) {
          outbs[o] = (bf16)gelu_f(v + bias[col]);
        } else {  // EPI == 5
          outbs[o] = (bf16)v;
        }
      }
    }
  }
}

// ---------------- fused attention, 128 q-rows/block, 64-key tiles -------------
__global__ __launch_bounds__(256) void attn_kernel(
    const bf16* __restrict__ qb, const bf16* __restrict__ kb,
    const bf16* __restrict__ vtb, bf16* __restrict__ operm) {
  __shared__ __align__(16) bf16 Ks[2][64 * 104];   // [key][dh], pad 104
  __shared__ __align__(16) bf16 Vs[2][96 * 72];    // [dh][key], pad 72
  __shared__ __align__(16) bf16 Ps[128 * 72];      // [qrow][key], pad 72
  int t = threadIdx.x;
  int w = t >> 6, lane = t & 63;
  int qd = lane >> 4, lr = lane & 15;
  int bh = blockIdx.x, nt0 = blockIdx.y * 128;
  int bq = bh >> 3, hh = bh & 7;

  const bf16* kgb = kb + (size_t)bh * 1024 * 96;
  const bf16* vgb = vtb + (size_t)bh * 96 * 1024;

  bf16x8 kreg[3], vreg[3];
#pragma unroll
  for (int it = 0; it < 3; it++) {
    int idx = it * 256 + t;
    kreg[it] = *(const bf16x8*)(kgb + (idx / 12) * 96 + (idx % 12) * 8);
    vreg[it] = *(const bf16x8*)(vgb + (size_t)(idx >> 3) * 1024 + (idx & 7) * 8);
  }

  const bf16* qg = qb + ((size_t)bh * 1024 + nt0 + w * 32) * 96;
  bf16x8 afq[2][3];
#pragma unroll
  for (int i = 0; i < 2; i++)
#pragma unroll
    for (int ks = 0; ks < 3; ks++)
      afq[i][ks] = *(const bf16x8*)(qg + (i * 16 + lr) * 96 + ks * 32 + qd * 8);

  f32x4 oacc[2][6] = {};
  float lst[2][4] = {};

  int cur = 0;
  for (int kt = 0; kt < 16; kt++) {
#pragma unroll
    for (int it = 0; it < 3; it++) {
      int idx = it * 256 + t;
      *(bf16x8*)&Ks[cur][(idx / 12) * 104 + (idx % 12) * 8] = kreg[it];
      *(bf16x8*)&Vs[cur][(idx >> 3) * 72 + (idx & 7) * 8] = vreg[it];
    }
    if (kt < 15) {
      const bf16* kg = kgb + (size_t)(kt + 1) * 64 * 96;
      const bf16* vg = vgb + (kt + 1) * 64;
#pragma unroll
      for (int it = 0; it < 3; it++) {
        int idx = it * 256 + t;
        kreg[it] = *(const bf16x8*)(kg + (idx / 12) * 96 + (idx % 12) * 8);
        vreg[it] =
            *(const bf16x8*)(vg + (size_t)(idx >> 3) * 1024 + (idx & 7) * 8);
      }
    }
    __syncthreads();

    f32x4 sacc[2][4] = {};
#pragma unroll
    for (int ks = 0; ks < 3; ks++) {
      bf16x8 bk[4];
#pragma unroll
      for (int jn = 0; jn < 4; jn++)
        bk[jn] =
            *(const bf16x8*)&Ks[cur][(jn * 16 + lr) * 104 + ks * 32 + qd * 8];
#pragma unroll
      for (int i = 0; i < 2; i++)
#pragma unroll
        for (int jn = 0; jn < 4; jn++)
          sacc[i][jn] = __builtin_amdgcn_mfma_f32_16x16x32_bf16(
              afq[i][ks], bk[jn], sacc[i][jn], 0, 0, 0);
    }

#pragma unroll
    for (int i = 0; i < 2; i++)
#pragma unroll
      for (int jn = 0; jn < 4; jn++)
#pragma unroll
        for (int r = 0; r < 4; r++) {
          float p = __expf(sacc[i][jn][r]);
          lst[i][r] += p;
          Ps[(w * 32 + i * 16 + qd * 4 + r) * 72 + jn * 16 + lr] = (bf16)p;
        }

#pragma unroll
    for (int ks = 0; ks < 2; ks++) {
      bf16x8 ap[2];
#pragma unroll
      for (int i = 0; i < 2; i++)
        ap[i] =
            *(const bf16x8*)&Ps[(w * 32 + i * 16 + lr) * 72 + ks * 32 + qd * 8];
#pragma unroll
      for (int jn = 0; jn < 6; jn++) {
        bf16x8 bv =
            *(const bf16x8*)&Vs[cur][(jn * 16 + lr) * 72 + ks * 32 + qd * 8];
#pragma unroll
        for (int i = 0; i < 2; i++)
          oacc[i][jn] = __builtin_amdgcn_mfma_f32_16x16x32_bf16(
              ap[i], bv, oacc[i][jn], 0, 0, 0);
      }
    }
    cur ^= 1;
  }

#pragma unroll
  for (int i = 0; i < 2; i++)
#pragma unroll
    for (int r = 0; r < 4; r++) {
#pragma unroll
      for (int off = 1; off < 16; off <<= 1)
        lst[i][r] += __shfl_xor(lst[i][r], off);
    }

#pragma unroll
  for (int i = 0; i < 2; i++) {
#pragma unroll
    for (int r = 0; r < 4; r++) {
      float inv = 1.0f / lst[i][r];
      int n = nt0 + w * 32 + i * 16 + qd * 4 + r;
      size_t rowo = (size_t)bq * 1024 + hh * 128 + (n >> 3);
      int colb = 96 * (n & 7);
#pragma unroll
      for (int jn = 0; jn < 6; jn++)
        operm[rowo * 768 + colb + jn * 16 + lr] =
            (bf16)(oacc[i][jn][r] * inv);
    }
  }
}

// ------------------------------------------------------------------------------
extern "C" void kernel_launch(void* const* d_in, const int* in_sizes, int n_in,
                              void* d_out, int out_size, void* d_ws,
                              size_t ws_size, hipStream_t stream) {
  const float* x = (const float*)d_in[0];
  const float* w_qkv = (const float*)d_in[1];
  const float* w_o = (const float*)d_in[2];
  const float* b_o = (const float*)d_in[3];
  const float* w1 = (const float*)d_in[4];
  const float* b1 = (const float*)d_in[5];
  const float* w2 = (const float*)d_in[6];
  const float* b2 = (const float*)d_in[7];
  const float* g1 = (const float*)d_in[8];
  const float* be1 = (const float*)d_in[9];
  const float* gm = (const float*)d_in[10];
  const float* bm = (const float*)d_in[11];
  const float* g3 = (const float*)d_in[12];
  const float* be3 = (const float*)d_in[13];

  char* ws = (char*)d_ws;
  size_t off = 0;
  auto alloc = [&](size_t bytes) {
    char* p = ws + off;
    off += (bytes + 255) & ~(size_t)255;
    return p;
  };
  const size_t SZ_TOK_BF = (size_t)M_TOK * 768 * 2;   // 12.58 MB
  bf16* fqkv = (bf16*)alloc((size_t)2304 * 768 * 2);
  bf16* fwo = (bf16*)alloc((size_t)768 * 768 * 2);
  bf16* fw1 = (bf16*)alloc((size_t)3072 * 768 * 2);
  bf16* fw2 = (bf16*)alloc((size_t)768 * 3072 * 2);
  bf16* hA = (bf16*)alloc(SZ_TOK_BF);   // LN1 out; then operm; then h2
  bf16* qb = (bf16*)alloc(SZ_TOK_BF);
  bf16* kbuf = (bf16*)alloc(SZ_TOK_BF);
  bf16* vtb = (bf16*)alloc(SZ_TOK_BF);
  bf16* x2 = (bf16*)alloc(SZ_TOK_BF);
  char* G = alloc((size_t)M_TOK * 3072 * 2);
  bf16* operm = hA;
  bf16* h2 = hA;
  bf16* pWo = (bf16*)G;
  bf16* a1 = (bf16*)G;
  bf16* pW2 = hA;  // spans hA+qb (2 x 12.58 MB), live after a1's last read

  make_frags_kernel<<<3456, 256, 0, stream>>>(w_qkv, w_o, w1, w2, fqkv, fwo,
                                              fw1, fw2);

  ln_kernel<<<M_TOK / 4, 256, 0, stream>>>(x, g1, be1, hA);

  // QKV GEMM (256^2 8-phase) with fused head-split epilogue
  gemm256_kernel<4, 768, 768, 768, 2304><<<dim3(32, 9), 512, 0, stream>>>(
      hA, fqkv, nullptr, nullptr, qb, kbuf, vtb);

  attn_kernel<<<dim3(64, 8), 256, 0, stream>>>(qb, kbuf, vtb, operm);

  // Wo GEMM (128^2), split-K=2 -> bf16 partials in G
  gemm128_kernel<5, 768, 768, 384, 768><<<dim3(64, 6, 2), 256, 0, stream>>>(
      operm, fwo, nullptr, pWo, nullptr, nullptr, nullptr);

  ln2_reduce_kernel<<<M_TOK / 4, 256, 0, stream>>>(pWo, b_o, x, gm, bm, x2, h2);

  // W1 GEMM (256^2 8-phase): bias + GELU -> bf16 a1
  gemm256_kernel<2, 768, 768, 768, 3072><<<dim3(32, 12), 512, 0, stream>>>(
      h2, fw1, b1, a1, nullptr, nullptr, nullptr);

  // W2 GEMM (256^2 8-phase), split-K=2 (slices of 1536) -> partials hA+qb
  gemm256_kernel<5, 3072, 3072, 1536, 768><<<dim3(32, 3, 2), 512, 0, stream>>>(
      a1, fw2, nullptr, pW2, nullptr, nullptr, nullptr);

  ln3_reduce_kernel<<<M_TOK / 4, 256, 0, stream>>>(pW2, b2, x2, g3, be3,
                                                   (float*)d_out);
}

// Round 9
// 338.174 us; speedup vs baseline: 1.0659x; 1.0659x over previous
//
#include <hip/hip_runtime.h>
#include <cmath>
#include <cstdint>

typedef __bf16 bf16;
typedef __bf16 bf16x8 __attribute__((ext_vector_type(8)));
typedef __bf16 bf16x4 __attribute__((ext_vector_type(4)));
typedef float  f32x4  __attribute__((ext_vector_type(4)));

#define M_TOK 8192
#define SCALE_ 0.10206207261596575f   // 96^-0.5
#define SB0 __builtin_amdgcn_sched_barrier(0)

__device__ __forceinline__ void gld_lds16(const void* g, void* l) {
  __builtin_amdgcn_global_load_lds(
      (__attribute__((address_space(1))) void*)(uintptr_t)g,
      (__attribute__((address_space(3))) void*)(uintptr_t)l,
      16, 0, 0);
}

// tanh-approx GELU (max |err| vs exact ~3e-3); tanh via v_exp_f32
__device__ __forceinline__ float gelu_f(float x) {
  float u = x * (0.7978845608f + 0.0356774081f * x * x);
  float t = 1.0f - 2.0f / (__expf(2.0f * u) + 1.0f);
  return 0.5f * x * (1.0f + t);
}

// ------- prep: weight->frag layout (blocks 0..3455) + LN1 (blocks 3456+) -----
// The two phases touch disjoint inputs (weights vs x) and are both
// memory-bound; one launch lets them co-schedule and saves a launch gap.
__global__ __launch_bounds__(256) void prep_kernel(
    const float* __restrict__ w_qkv, const float* __restrict__ w_o,
    const float* __restrict__ w1, const float* __restrict__ w2,
    bf16* __restrict__ fqkv, bf16* __restrict__ fwo, bf16* __restrict__ fw1,
    bf16* __restrict__ fw2, const float* __restrict__ x,
    const float* __restrict__ g, const float* __restrict__ b,
    bf16* __restrict__ ob) {
  if (blockIdx.x < 3456) {
    int chunk = blockIdx.x * 4 + (threadIdx.x >> 6);
    int lane = threadIdx.x & 63;
    const float* src;
    bf16* dst;
    int K, N, base;
    if (chunk < 3456) {
      src = w_qkv; dst = fqkv; K = 768; N = 2304; base = 0;
    } else if (chunk < 4608) {
      src = w_o; dst = fwo; K = 768; N = 768; base = 3456;
    } else if (chunk < 9216) {
      src = w1; dst = fw1; K = 768; N = 3072; base = 4608;
    } else {
      src = w2; dst = fw2; K = 3072; N = 768; base = 9216;
    }
    int lid = chunk - base;
    int kc = K / 32;
    int n16 = lid / kc, c = lid - n16 * kc;
    int lr = lane & 15, qd = lane >> 4;
    int n = n16 * 16 + lr;
    int k0 = c * 32 + qd * 8;
    bf16x8 v;
#pragma unroll
    for (int e = 0; e < 8; e++) v[e] = (bf16)src[(size_t)(k0 + e) * N + n];
    *(bf16x8*)&dst[(size_t)lid * 512 + lane * 8] = v;
  } else {
    int w = threadIdx.x >> 6, lane = threadIdx.x & 63;
    size_t row = (size_t)(blockIdx.x - 3456) * 4 + w;
    const float* xr = x + row * 768;
    float4 v[3];
    float s = 0.f, sq = 0.f;
#pragma unroll
    for (int k = 0; k < 3; k++) {
      v[k] = *(const float4*)(xr + (k * 64 + lane) * 4);
      s += v[k].x + v[k].y + v[k].z + v[k].w;
      sq += v[k].x * v[k].x + v[k].y * v[k].y + v[k].z * v[k].z +
            v[k].w * v[k].w;
    }
#pragma unroll
    for (int off = 32; off >= 1; off >>= 1) {
      s += __shfl_xor(s, off);
      sq += __shfl_xor(sq, off);
    }
    float mean = s * (1.f / 768.f);
    float rstd = rsqrtf(sq * (1.f / 768.f) - mean * mean + 1e-5f);
#pragma unroll
    for (int k = 0; k < 3; k++) {
      int c = (k * 64 + lane) * 4;
      float4 gg = *(const float4*)(g + c);
      float4 bb = *(const float4*)(b + c);
      bf16x4 pk = {(bf16)((v[k].x - mean) * rstd * gg.x + bb.x),
                   (bf16)((v[k].y - mean) * rstd * gg.y + bb.y),
                   (bf16)((v[k].z - mean) * rstd * gg.z + bb.z),
                   (bf16)((v[k].w - mean) * rstd * gg.w + bb.w)};
      *(bf16x4*)(ob + row * 768 + c) = pk;
    }
  }
}

// ------- ln2_reduce: t = p0+p1+b_o+x(resid f32); x2=t (bf16); h2 = LN(t) bf16 -
__global__ __launch_bounds__(256) void ln2_reduce_kernel(
    const bf16* __restrict__ p, const float* __restrict__ bo,
    const float* __restrict__ xres, const float* __restrict__ g,
    const float* __restrict__ b, bf16* __restrict__ x2,
    bf16* __restrict__ h2) {
  int w = threadIdx.x >> 6, lane = threadIdx.x & 63;
  size_t row = (size_t)blockIdx.x * 4 + w;
  const bf16* p0 = p + row * 768;
  const bf16* p1 = p0 + (size_t)M_TOK * 768;
  const float* xr = xres + row * 768;
  float4 v[3];
  float s = 0.f, sq = 0.f;
#pragma unroll
  for (int k = 0; k < 3; k++) {
    int c = (k * 64 + lane) * 4;
    bf16x4 a0 = *(const bf16x4*)(p0 + c);
    bf16x4 a1 = *(const bf16x4*)(p1 + c);
    float4 bb = *(const float4*)(bo + c);
    float4 rr = *(const float4*)(xr + c);
    v[k].x = (float)a0[0] + (float)a1[0] + bb.x + rr.x;
    v[k].y = (float)a0[1] + (float)a1[1] + bb.y + rr.y;
    v[k].z = (float)a0[2] + (float)a1[2] + bb.z + rr.z;
    v[k].w = (float)a0[3] + (float)a1[3] + bb.w + rr.w;
    bf16x4 xo = {(bf16)v[k].x, (bf16)v[k].y, (bf16)v[k].z, (bf16)v[k].w};
    *(bf16x4*)(x2 + row * 768 + c) = xo;
    s += v[k].x + v[k].y + v[k].z + v[k].w;
    sq += v[k].x * v[k].x + v[k].y * v[k].y + v[k].z * v[k].z + v[k].w * v[k].w;
  }
#pragma unroll
  for (int off = 32; off >= 1; off >>= 1) {
    s += __shfl_xor(s, off);
    sq += __shfl_xor(sq, off);
  }
  float mean = s * (1.f / 768.f);
  float rstd = rsqrtf(sq * (1.f / 768.f) - mean * mean + 1e-5f);
#pragma unroll
  for (int k = 0; k < 3; k++) {
    int c = (k * 64 + lane) * 4;
    float4 gg = *(const float4*)(g + c);
    float4 bb = *(const float4*)(b + c);
    bf16x4 pk = {(bf16)((v[k].x - mean) * rstd * gg.x + bb.x),
                 (bf16)((v[k].y - mean) * rstd * gg.y + bb.y),
                 (bf16)((v[k].z - mean) * rstd * gg.z + bb.z),
                 (bf16)((v[k].w - mean) * rstd * gg.w + bb.w)};
    *(bf16x4*)(h2 + row * 768 + c) = pk;
  }
}

// ------- ln3_reduce: t = gelu(p0+p1+b2)+x2(bf16); out = LN(t) f32 -------------
__global__ __launch_bounds__(256) void ln3_reduce_kernel(
    const bf16* __restrict__ p, const float* __restrict__ b2,
    const bf16* __restrict__ x2, const float* __restrict__ g,
    const float* __restrict__ b, float* __restrict__ out) {
  int w = threadIdx.x >> 6, lane = threadIdx.x & 63;
  size_t row = (size_t)blockIdx.x * 4 + w;
  const bf16* p0 = p + row * 768;
  const bf16* p1 = p0 + (size_t)M_TOK * 768;
  const bf16* xr = x2 + row * 768;
  float4 v[3];
  float s = 0.f, sq = 0.f;
#pragma unroll
  for (int k = 0; k < 3; k++) {
    int c = (k * 64 + lane) * 4;
    bf16x4 a0 = *(const bf16x4*)(p0 + c);
    bf16x4 a1 = *(const bf16x4*)(p1 + c);
    float4 bb = *(const float4*)(b2 + c);
    bf16x4 rr = *(const bf16x4*)(xr + c);
    v[k].x = gelu_f((float)a0[0] + (float)a1[0] + bb.x) + (float)rr[0];
    v[k].y = gelu_f((float)a0[1] + (float)a1[1] + bb.y) + (float)rr[1];
    v[k].z = gelu_f((float)a0[2] + (float)a1[2] + bb.z) + (float)rr[2];
    v[k].w = gelu_f((float)a0[3] + (float)a1[3] + bb.w) + (float)rr[3];
    s += v[k].x + v[k].y + v[k].z + v[k].w;
    sq += v[k].x * v[k].x + v[k].y * v[k].y + v[k].z * v[k].z + v[k].w * v[k].w;
  }
#pragma unroll
  for (int off = 32; off >= 1; off >>= 1) {
    s += __shfl_xor(s, off);
    sq += __shfl_xor(sq, off);
  }
  float mean = s * (1.f / 768.f);
  float rstd = rsqrtf(sq * (1.f / 768.f) - mean * mean + 1e-5f);
#pragma unroll
  for (int k = 0; k < 3; k++) {
    int c = (k * 64 + lane) * 4;
    float4 gg = *(const float4*)(g + c);
    float4 bb = *(const float4*)(b + c);
    float4 ov = {(v[k].x - mean) * rstd * gg.x + bb.x,
                 (v[k].y - mean) * rstd * gg.y + bb.y,
                 (v[k].z - mean) * rstd * gg.z + bb.z,
                 (v[k].w - mean) * rstd * gg.w + bb.w};
    *(float4*)(out + row * 768 + c) = ov;
  }
}

// ---------------- GEMM: C = A @ B^T, 128x128 (R7 best, banked) ---------------
// 3 blocks/CU (BK=32, 3x16KB triple buffer), counted vmcnt(4), one barrier
// per K-tile, setprio on MFMA, XCD supertile remap. 4 schedule variants and
// 2 256^2 ports all failed to beat this (R3..R8); it is the GEMM engine.
template <int EPI, int LDA, int KTOT, int KSL, int NN>
__global__ __launch_bounds__(256, 3) void gemm128_kernel(
    const bf16* __restrict__ A, const bf16* __restrict__ Bf,
    const float* __restrict__ bias, bf16* __restrict__ outb,
    bf16* __restrict__ qo, bf16* __restrict__ ko, bf16* __restrict__ vto) {
  constexpr int KCg = KTOT / 32;
  constexpr int NT = KSL / 32;
  __shared__ __align__(16) bf16 smem[3][8192];
  int tid = threadIdx.x;
  int w = tid >> 6, l = tid & 63;
  int qd = l >> 4, lr = l & 15;
  int id2 = blockIdx.y * gridDim.x + blockIdx.x;
  int xcd = id2 & 7;
  int slot = id2 >> 3;
  int Mg = gridDim.x >> 3;
  int mt = xcd * Mg + (slot % Mg);
  int ntl = slot / Mg;
  int bm0 = mt * 128, bn0 = ntl * 128;
  int kb = blockIdx.z * KSL;
  int wm = (w >> 1) * 64, wn = (w & 1) * 64;
  int wnl = (w & 1) * 4;

  const bf16* pA = A + (size_t)(bm0 + w * 32 + (l >> 2)) * LDA + kb +
                   (((l & 3) ^ ((l >> 3) & 3)) * 8);
  const bf16* pB =
      Bf + ((size_t)((bn0 >> 4) + w * 2) * KCg + (kb >> 5)) * 512 + l * 8;

  auto STG = [&](int t, int b) {
    char* dA = (char*)smem[b] + w * 2048;
    char* dB = (char*)smem[b] + 8192 + w * 2048;
    gld_lds16(pA + t * 32, dA);
    gld_lds16(pA + t * 32 + (size_t)16 * LDA, dA + 1024);
    gld_lds16(pB + (size_t)t * 512, dB);
    gld_lds16(pB + (size_t)KCg * 512 + (size_t)t * 512, dB + 1024);
  };
  auto LDF = [&](int b, bf16x8* af, bf16x8* bv) {
    const bf16* Ab = smem[b];
    const bf16* Bb = smem[b] + 4096;
#pragma unroll
    for (int i = 0; i < 4; ++i) {
      int r = wm + i * 16 + lr;
      af[i] = *(const bf16x8*)(Ab + r * 32 + ((qd ^ ((lr >> 1) & 3)) * 8));
    }
#pragma unroll
    for (int j = 0; j < 4; ++j)
      bv[j] = *(const bf16x8*)(Bb + (wnl + j) * 512 + l * 8);
  };

  f32x4 acc[4][4] = {};

  STG(0, 0);
  STG(1, 1);
  asm volatile("s_waitcnt vmcnt(4)" ::: "memory");
  SB0;
  __builtin_amdgcn_s_barrier();

#pragma unroll 1
  for (int t3 = 0; t3 < NT; t3 += 3) {
#pragma unroll
    for (int u = 0; u < 3; ++u) {
      const int t = t3 + u;
      const bool st = (t + 2) < NT;
      if (st) STG(t + 2, (u + 2) % 3);
      SB0;
      bf16x8 af[4], bv[4];
      LDF(u, af, bv);
      asm volatile("s_waitcnt lgkmcnt(0)" ::: "memory");
      SB0;
      __builtin_amdgcn_s_setprio(1);
#pragma unroll
      for (int i = 0; i < 4; ++i)
#pragma unroll
        for (int j = 0; j < 4; ++j)
          acc[i][j] = __builtin_amdgcn_mfma_f32_16x16x32_bf16(
              af[i], bv[j], acc[i][j], 0, 0, 0);
      __builtin_amdgcn_s_setprio(0);
      if (t + 1 < NT) {
        if (st) asm volatile("s_waitcnt vmcnt(4)" ::: "memory");
        else    asm volatile("s_waitcnt vmcnt(0)" ::: "memory");
        SB0;
        __builtin_amdgcn_s_barrier();
      }
    }
  }

  bf16* outbs = (EPI == 5) ? outb + (size_t)blockIdx.z * M_TOK * NN : outb;

#pragma unroll
  for (int i = 0; i < 4; i++) {
#pragma unroll
    for (int j = 0; j < 4; j++) {
      if (EPI == 4) {
        // fused qkv split (NN==2304). 16-col tiles never straddle head bounds.
        int colt = bn0 + wn + j * 16;
        int which = colt / 768;
        int rem = colt - which * 768;
        int h = rem / 96;
        int dhb = rem - h * 96;
        int row0 = bm0 + wm + i * 16 + qd * 4;
        int b = row0 >> 10, n0 = row0 & 1023;
        int bh = b * 8 + h;
        if (which == 2) {
          bf16x4 pk = {(bf16)acc[i][j][0], (bf16)acc[i][j][1],
                       (bf16)acc[i][j][2], (bf16)acc[i][j][3]};
          *(bf16x4*)(vto + ((size_t)(bh * 96 + dhb + lr)) * 1024 + n0) = pk;
        } else if (which == 0) {
          // q pre-scaled by 1/sqrt(dh) so attention skips the S-scale
#pragma unroll
          for (int r = 0; r < 4; r++)
            qo[((size_t)bh * 1024 + n0 + r) * 96 + dhb + lr] =
                (bf16)(acc[i][j][r] * SCALE_);
        } else {
#pragma unroll
          for (int r = 0; r < 4; r++)
            ko[((size_t)bh * 1024 + n0 + r) * 96 + dhb + lr] =
                (bf16)acc[i][j][r];
        }
      } else {
#pragma unroll
        for (int r = 0; r < 4; r++) {
          int row = bm0 + wm + i * 16 + qd * 4 + r;
          int col = bn0 + wn + j * 16 + lr;
          size_t o = (size_t)row * NN + col;
          float v = acc[i][j][r];
          if (EPI == 2) {
            outbs[o] = (bf16)gelu_f(v + bias[col]);
          } else {  // EPI == 5
            outbs[o] = (bf16)v;
          }
        }
      }
    }
  }
}

// ---------------- fused attention, 128 q-rows/block, 64-key tiles -------------
// R9: + setprio(1/0) around MFMA clusters (T5; attn = 2 independent
// blocks/CU, the regime where priority arbitration pays, m191).
__global__ __launch_bounds__(256) void attn_kernel(
    const bf16* __restrict__ qb, const bf16* __restrict__ kb,
    const bf16* __restrict__ vtb, bf16* __restrict__ operm) {
  __shared__ __align__(16) bf16 Ks[2][64 * 104];   // [key][dh], pad 104
  __shared__ __align__(16) bf16 Vs[2][96 * 72];    // [dh][key], pad 72
  __shared__ __align__(16) bf16 Ps[128 * 72];      // [qrow][key], pad 72
  int t = threadIdx.x;
  int w = t >> 6, lane = t & 63;
  int qd = lane >> 4, lr = lane & 15;
  int bh = blockIdx.x, nt0 = blockIdx.y * 128;
  int bq = bh >> 3, hh = bh & 7;

  const bf16* kgb = kb + (size_t)bh * 1024 * 96;
  const bf16* vgb = vtb + (size_t)bh * 96 * 1024;

  bf16x8 kreg[3], vreg[3];
#pragma unroll
  for (int it = 0; it < 3; it++) {
    int idx = it * 256 + t;
    kreg[it] = *(const bf16x8*)(kgb + (idx / 12) * 96 + (idx % 12) * 8);
    vreg[it] = *(const bf16x8*)(vgb + (size_t)(idx >> 3) * 1024 + (idx & 7) * 8);
  }

  const bf16* qg = qb + ((size_t)bh * 1024 + nt0 + w * 32) * 96;
  bf16x8 afq[2][3];
#pragma unroll
  for (int i = 0; i < 2; i++)
#pragma unroll
    for (int ks = 0; ks < 3; ks++)
      afq[i][ks] = *(const bf16x8*)(qg + (i * 16 + lr) * 96 + ks * 32 + qd * 8);

  f32x4 oacc[2][6] = {};
  float lst[2][4] = {};

  int cur = 0;
  for (int kt = 0; kt < 16; kt++) {
#pragma unroll
    for (int it = 0; it < 3; it++) {
      int idx = it * 256 + t;
      *(bf16x8*)&Ks[cur][(idx / 12) * 104 + (idx % 12) * 8] = kreg[it];
      *(bf16x8*)&Vs[cur][(idx >> 3) * 72 + (idx & 7) * 8] = vreg[it];
    }
    if (kt < 15) {
      const bf16* kg = kgb + (size_t)(kt + 1) * 64 * 96;
      const bf16* vg = vgb + (kt + 1) * 64;
#pragma unroll
      for (int it = 0; it < 3; it++) {
        int idx = it * 256 + t;
        kreg[it] = *(const bf16x8*)(kg + (idx / 12) * 96 + (idx % 12) * 8);
        vreg[it] =
            *(const bf16x8*)(vg + (size_t)(idx >> 3) * 1024 + (idx & 7) * 8);
      }
    }
    __syncthreads();

    f32x4 sacc[2][4] = {};
    __builtin_amdgcn_s_setprio(1);
#pragma unroll
    for (int ks = 0; ks < 3; ks++) {
      bf16x8 bk[4];
#pragma unroll
      for (int jn = 0; jn < 4; jn++)
        bk[jn] =
            *(const bf16x8*)&Ks[cur][(jn * 16 + lr) * 104 + ks * 32 + qd * 8];
#pragma unroll
      for (int i = 0; i < 2; i++)
#pragma unroll
        for (int jn = 0; jn < 4; jn++)
          sacc[i][jn] = __builtin_amdgcn_mfma_f32_16x16x32_bf16(
              afq[i][ks], bk[jn], sacc[i][jn], 0, 0, 0);
    }
    __builtin_amdgcn_s_setprio(0);

#pragma unroll
    for (int i = 0; i < 2; i++)
#pragma unroll
      for (int jn = 0; jn < 4; jn++)
#pragma unroll
        for (int r = 0; r < 4; r++) {
          float p = __expf(sacc[i][jn][r]);
          lst[i][r] += p;
          Ps[(w * 32 + i * 16 + qd * 4 + r) * 72 + jn * 16 + lr] = (bf16)p;
        }

    __builtin_amdgcn_s_setprio(1);
#pragma unroll
    for (int ks = 0; ks < 2; ks++) {
      bf16x8 ap[2];
#pragma unroll
      for (int i = 0; i < 2; i++)
        ap[i] =
            *(const bf16x8*)&Ps[(w * 32 + i * 16 + lr) * 72 + ks * 32 + qd * 8];
#pragma unroll
      for (int jn = 0; jn < 6; jn++) {
        bf16x8 bv =
            *(const bf16x8*)&Vs[cur][(jn * 16 + lr) * 72 + ks * 32 + qd * 8];
#pragma unroll
        for (int i = 0; i < 2; i++)
          oacc[i][jn] = __builtin_amdgcn_mfma_f32_16x16x32_bf16(
              ap[i], bv, oacc[i][jn], 0, 0, 0);
      }
    }
    __builtin_amdgcn_s_setprio(0);
    cur ^= 1;
  }

#pragma unroll
  for (int i = 0; i < 2; i++)
#pragma unroll
    for (int r = 0; r < 4; r++) {
#pragma unroll
      for (int off = 1; off < 16; off <<= 1)
        lst[i][r] += __shfl_xor(lst[i][r], off);
    }

#pragma unroll
  for (int i = 0; i < 2; i++) {
#pragma unroll
    for (int r = 0; r < 4; r++) {
      float inv = 1.0f / lst[i][r];
      int n = nt0 + w * 32 + i * 16 + qd * 4 + r;
      size_t rowo = (size_t)bq * 1024 + hh * 128 + (n >> 3);
      int colb = 96 * (n & 7);
#pragma unroll
      for (int jn = 0; jn < 6; jn++)
        operm[rowo * 768 + colb + jn * 16 + lr] =
            (bf16)(oacc[i][jn][r] * inv);
    }
  }
}

// ------------------------------------------------------------------------------
extern "C" void kernel_launch(void* const* d_in, const int* in_sizes, int n_in,
                              void* d_out, int out_size, void* d_ws,
                              size_t ws_size, hipStream_t stream) {
  const float* x = (const float*)d_in[0];
  const float* w_qkv = (const float*)d_in[1];
  const float* w_o = (const float*)d_in[2];
  const float* b_o = (const float*)d_in[3];
  const float* w1 = (const float*)d_in[4];
  const float* b1 = (const float*)d_in[5];
  const float* w2 = (const float*)d_in[6];
  const float* b2 = (const float*)d_in[7];
  const float* g1 = (const float*)d_in[8];
  const float* be1 = (const float*)d_in[9];
  const float* gm = (const float*)d_in[10];
  const float* bm = (const float*)d_in[11];
  const float* g3 = (const float*)d_in[12];
  const float* be3 = (const float*)d_in[13];

  char* ws = (char*)d_ws;
  size_t off = 0;
  auto alloc = [&](size_t bytes) {
    char* p = ws + off;
    off += (bytes + 255) & ~(size_t)255;
    return p;
  };
  const size_t SZ_TOK_BF = (size_t)M_TOK * 768 * 2;   // 12.58 MB
  bf16* fqkv = (bf16*)alloc((size_t)2304 * 768 * 2);
  bf16* fwo = (bf16*)alloc((size_t)768 * 768 * 2);
  bf16* fw1 = (bf16*)alloc((size_t)3072 * 768 * 2);
  bf16* fw2 = (bf16*)alloc((size_t)768 * 3072 * 2);
  bf16* hA = (bf16*)alloc(SZ_TOK_BF);   // LN1 out; then operm; then h2
  bf16* qb = (bf16*)alloc(SZ_TOK_BF);
  bf16* kbuf = (bf16*)alloc(SZ_TOK_BF);
  bf16* vtb = (bf16*)alloc(SZ_TOK_BF);
  bf16* x2 = (bf16*)alloc(SZ_TOK_BF);
  char* G = alloc((size_t)M_TOK * 3072 * 2);
  bf16* operm = hA;
  bf16* h2 = hA;
  bf16* pWo = (bf16*)G;
  bf16* a1 = (bf16*)G;
  bf16* pW2 = hA;  // spans hA+qb (2 x 12.58 MB), live after a1's last read

  // frags (blocks 0..3455) + LN1 (blocks 3456..5503) in one launch
  prep_kernel<<<5504, 256, 0, stream>>>(w_qkv, w_o, w1, w2, fqkv, fwo, fw1,
                                        fw2, x, g1, be1, hA);

  // QKV GEMM with fused head-split epilogue (q pre-scaled by 1/sqrt(dh))
  gemm128_kernel<4, 768, 768, 768, 2304><<<dim3(64, 18), 256, 0, stream>>>(
      hA, fqkv, nullptr, nullptr, qb, kbuf, vtb);

  attn_kernel<<<dim3(64, 8), 256, 0, stream>>>(qb, kbuf, vtb, operm);

  // Wo GEMM, split-K=2 (slices of 384) -> bf16 partials in G
  gemm128_kernel<5, 768, 768, 384, 768><<<dim3(64, 6, 2), 256, 0, stream>>>(
      operm, fwo, nullptr, pWo, nullptr, nullptr, nullptr);

  ln2_reduce_kernel<<<M_TOK / 4, 256, 0, stream>>>(pWo, b_o, x, gm, bm, x2, h2);

  // W1 GEMM: bias + GELU -> bf16 a1
  gemm128_kernel<2, 768, 768, 768, 3072><<<dim3(64, 24), 256, 0, stream>>>(
      h2, fw1, b1, a1, nullptr, nullptr, nullptr);

  // W2 GEMM, split-K=2 (slices of 1536) -> bf16 partials spanning hA+qb
  gemm128_kernel<5, 3072, 3072, 1536, 768><<<dim3(64, 6, 2), 256, 0, stream>>>(
      a1, fw2, nullptr, pW2, nullptr, nullptr, nullptr);

  ln3_reduce_kernel<<<M_TOK / 4, 256, 0, stream>>>(pW2, b2, x2, g3, be3,
                                                   (float*)d_out);
}

// Round 10
// 318.957 us; speedup vs baseline: 1.1301x; 1.0602x over previous
//
#include <hip/hip_runtime.h>
#include <cmath>
#include <cstdint>

typedef __bf16 bf16;
typedef __bf16 bf16x8 __attribute__((ext_vector_type(8)));
typedef __bf16 bf16x4 __attribute__((ext_vector_type(4)));
typedef float  f32x4  __attribute__((ext_vector_type(4)));

#define M_TOK 8192
#define SCALE_ 0.10206207261596575f   // 96^-0.5
#define SB0 __builtin_amdgcn_sched_barrier(0)

__device__ __forceinline__ void gld_lds16(const void* g, void* l) {
  __builtin_amdgcn_global_load_lds(
      (__attribute__((address_space(1))) void*)(uintptr_t)g,
      (__attribute__((address_space(3))) void*)(uintptr_t)l,
      16, 0, 0);
}

// tanh-approx GELU (max |err| vs exact ~3e-3); tanh via v_exp_f32
__device__ __forceinline__ float gelu_f(float x) {
  float u = x * (0.7978845608f + 0.0356774081f * x * x);
  float t = 1.0f - 2.0f / (__expf(2.0f * u) + 1.0f);
  return 0.5f * x * (1.0f + t);
}

// ------- weight -> MFMA-fragment layout (B-operand order), all 4 weights -----
__global__ __launch_bounds__(256) void make_frags_kernel(
    const float* __restrict__ w_qkv, const float* __restrict__ w_o,
    const float* __restrict__ w1, const float* __restrict__ w2,
    bf16* __restrict__ fqkv, bf16* __restrict__ fwo, bf16* __restrict__ fw1,
    bf16* __restrict__ fw2) {
  int chunk = blockIdx.x * 4 + (threadIdx.x >> 6);
  int lane = threadIdx.x & 63;
  const float* src;
  bf16* dst;
  int K, N, base;
  if (chunk < 3456) {
    src = w_qkv; dst = fqkv; K = 768; N = 2304; base = 0;
  } else if (chunk < 4608) {
    src = w_o; dst = fwo; K = 768; N = 768; base = 3456;
  } else if (chunk < 9216) {
    src = w1; dst = fw1; K = 768; N = 3072; base = 4608;
  } else {
    src = w2; dst = fw2; K = 3072; N = 768; base = 9216;
  }
  int lid = chunk - base;
  int kc = K / 32;
  int n16 = lid / kc, c = lid - n16 * kc;
  int lr = lane & 15, qd = lane >> 4;
  int n = n16 * 16 + lr;
  int k0 = c * 32 + qd * 8;
  bf16x8 v;
#pragma unroll
  for (int e = 0; e < 8; e++) v[e] = (bf16)src[(size_t)(k0 + e) * N + n];
  *(bf16x8*)&dst[(size_t)lid * 512 + lane * 8] = v;
}

// ---------------- layernorm (f32 in -> bf16 out), one wave per row ------------
__global__ __launch_bounds__(256) void ln_kernel(
    const float* __restrict__ x, const float* __restrict__ g,
    const float* __restrict__ b, bf16* __restrict__ ob) {
  int w = threadIdx.x >> 6, lane = threadIdx.x & 63;
  size_t row = (size_t)blockIdx.x * 4 + w;
  const float* xr = x + row * 768;
  float4 v[3];
  float s = 0.f, sq = 0.f;
#pragma unroll
  for (int k = 0; k < 3; k++) {
    v[k] = *(const float4*)(xr + (k * 64 + lane) * 4);
    s += v[k].x + v[k].y + v[k].z + v[k].w;
    sq += v[k].x * v[k].x + v[k].y * v[k].y + v[k].z * v[k].z + v[k].w * v[k].w;
  }
#pragma unroll
  for (int off = 32; off >= 1; off >>= 1) {
    s += __shfl_xor(s, off);
    sq += __shfl_xor(sq, off);
  }
  float mean = s * (1.f / 768.f);
  float rstd = rsqrtf(sq * (1.f / 768.f) - mean * mean + 1e-5f);
#pragma unroll
  for (int k = 0; k < 3; k++) {
    int c = (k * 64 + lane) * 4;
    float4 gg = *(const float4*)(g + c);
    float4 bb = *(const float4*)(b + c);
    bf16x4 pk = {(bf16)((v[k].x - mean) * rstd * gg.x + bb.x),
                 (bf16)((v[k].y - mean) * rstd * gg.y + bb.y),
                 (bf16)((v[k].z - mean) * rstd * gg.z + bb.z),
                 (bf16)((v[k].w - mean) * rstd * gg.w + bb.w)};
    *(bf16x4*)(ob + row * 768 + c) = pk;
  }
}

// ------- ln3_reduce: t = gelu(p0+p1+b2)+x2(bf16); out = LN(t) f32 -------------
__global__ __launch_bounds__(256) void ln3_reduce_kernel(
    const bf16* __restrict__ p, const float* __restrict__ b2,
    const bf16* __restrict__ x2, const float* __restrict__ g,
    const float* __restrict__ b, float* __restrict__ out) {
  int w = threadIdx.x >> 6, lane = threadIdx.x & 63;
  size_t row = (size_t)blockIdx.x * 4 + w;
  const bf16* p0 = p + row * 768;
  const bf16* p1 = p0 + (size_t)M_TOK * 768;
  const bf16* xr = x2 + row * 768;
  float4 v[3];
  float s = 0.f, sq = 0.f;
#pragma unroll
  for (int k = 0; k < 3; k++) {
    int c = (k * 64 + lane) * 4;
    bf16x4 a0 = *(const bf16x4*)(p0 + c);
    bf16x4 a1 = *(const bf16x4*)(p1 + c);
    float4 bb = *(const float4*)(b2 + c);
    bf16x4 rr = *(const bf16x4*)(xr + c);
    v[k].x = gelu_f((float)a0[0] + (float)a1[0] + bb.x) + (float)rr[0];
    v[k].y = gelu_f((float)a0[1] + (float)a1[1] + bb.y) + (float)rr[1];
    v[k].z = gelu_f((float)a0[2] + (float)a1[2] + bb.z) + (float)rr[2];
    v[k].w = gelu_f((float)a0[3] + (float)a1[3] + bb.w) + (float)rr[3];
    s += v[k].x + v[k].y + v[k].z + v[k].w;
    sq += v[k].x * v[k].x + v[k].y * v[k].y + v[k].z * v[k].z + v[k].w * v[k].w;
  }
#pragma unroll
  for (int off = 32; off >= 1; off >>= 1) {
    s += __shfl_xor(s, off);
    sq += __shfl_xor(sq, off);
  }
  float mean = s * (1.f / 768.f);
  float rstd = rsqrtf(sq * (1.f / 768.f) - mean * mean + 1e-5f);
#pragma unroll
  for (int k = 0; k < 3; k++) {
    int c = (k * 64 + lane) * 4;
    float4 gg = *(const float4*)(g + c);
    float4 bb = *(const float4*)(b + c);
    float4 ov = {(v[k].x - mean) * rstd * gg.x + bb.x,
                 (v[k].y - mean) * rstd * gg.y + bb.y,
                 (v[k].z - mean) * rstd * gg.z + bb.z,
                 (v[k].w - mean) * rstd * gg.w + bb.w};
    *(float4*)(out + row * 768 + c) = ov;
  }
}

// ---------------- GEMM: C = A @ B^T, 128x128 (R7 best, banked) ---------------
template <int EPI, int LDA, int KTOT, int KSL, int NN>
__global__ __launch_bounds__(256, 3) void gemm128_kernel(
    const bf16* __restrict__ A, const bf16* __restrict__ Bf,
    const float* __restrict__ bias, bf16* __restrict__ outb,
    bf16* __restrict__ qo, bf16* __restrict__ ko, bf16* __restrict__ vto) {
  constexpr int KCg = KTOT / 32;
  constexpr int NT = KSL / 32;
  __shared__ __align__(16) bf16 smem[3][8192];
  int tid = threadIdx.x;
  int w = tid >> 6, l = tid & 63;
  int qd = l >> 4, lr = l & 15;
  int id2 = blockIdx.y * gridDim.x + blockIdx.x;
  int xcd = id2 & 7;
  int slot = id2 >> 3;
  int Mg = gridDim.x >> 3;
  int mt = xcd * Mg + (slot % Mg);
  int ntl = slot / Mg;
  int bm0 = mt * 128, bn0 = ntl * 128;
  int kb = blockIdx.z * KSL;
  int wm = (w >> 1) * 64, wn = (w & 1) * 64;
  int wnl = (w & 1) * 4;

  const bf16* pA = A + (size_t)(bm0 + w * 32 + (l >> 2)) * LDA + kb +
                   (((l & 3) ^ ((l >> 3) & 3)) * 8);
  const bf16* pB =
      Bf + ((size_t)((bn0 >> 4) + w * 2) * KCg + (kb >> 5)) * 512 + l * 8;

  auto STG = [&](int t, int b) {
    char* dA = (char*)smem[b] + w * 2048;
    char* dB = (char*)smem[b] + 8192 + w * 2048;
    gld_lds16(pA + t * 32, dA);
    gld_lds16(pA + t * 32 + (size_t)16 * LDA, dA + 1024);
    gld_lds16(pB + (size_t)t * 512, dB);
    gld_lds16(pB + (size_t)KCg * 512 + (size_t)t * 512, dB + 1024);
  };
  auto LDF = [&](int b, bf16x8* af, bf16x8* bv) {
    const bf16* Ab = smem[b];
    const bf16* Bb = smem[b] + 4096;
#pragma unroll
    for (int i = 0; i < 4; ++i) {
      int r = wm + i * 16 + lr;
      af[i] = *(const bf16x8*)(Ab + r * 32 + ((qd ^ ((lr >> 1) & 3)) * 8));
    }
#pragma unroll
    for (int j = 0; j < 4; ++j)
      bv[j] = *(const bf16x8*)(Bb + (wnl + j) * 512 + l * 8);
  };

  f32x4 acc[4][4] = {};

  STG(0, 0);
  STG(1, 1);
  asm volatile("s_waitcnt vmcnt(4)" ::: "memory");
  SB0;
  __builtin_amdgcn_s_barrier();

#pragma unroll 1
  for (int t3 = 0; t3 < NT; t3 += 3) {
#pragma unroll
    for (int u = 0; u < 3; ++u) {
      const int t = t3 + u;
      const bool st = (t + 2) < NT;
      if (st) STG(t + 2, (u + 2) % 3);
      SB0;
      bf16x8 af[4], bv[4];
      LDF(u, af, bv);
      asm volatile("s_waitcnt lgkmcnt(0)" ::: "memory");
      SB0;
      __builtin_amdgcn_s_setprio(1);
#pragma unroll
      for (int i = 0; i < 4; ++i)
#pragma unroll
        for (int j = 0; j < 4; ++j)
          acc[i][j] = __builtin_amdgcn_mfma_f32_16x16x32_bf16(
              af[i], bv[j], acc[i][j], 0, 0, 0);
      __builtin_amdgcn_s_setprio(0);
      if (t + 1 < NT) {
        if (st) asm volatile("s_waitcnt vmcnt(4)" ::: "memory");
        else    asm volatile("s_waitcnt vmcnt(0)" ::: "memory");
        SB0;
        __builtin_amdgcn_s_barrier();
      }
    }
  }

  bf16* outbs = (EPI == 5) ? outb + (size_t)blockIdx.z * M_TOK * NN : outb;

#pragma unroll
  for (int i = 0; i < 4; i++) {
#pragma unroll
    for (int j = 0; j < 4; j++) {
      if (EPI == 4) {
        // fused qkv split (NN==2304). 16-col tiles never straddle head bounds.
        int colt = bn0 + wn + j * 16;
        int which = colt / 768;
        int rem = colt - which * 768;
        int h = rem / 96;
        int dhb = rem - h * 96;
        int row0 = bm0 + wm + i * 16 + qd * 4;
        int b = row0 >> 10, n0 = row0 & 1023;
        int bh = b * 8 + h;
        if (which == 2) {
          bf16x4 pk = {(bf16)acc[i][j][0], (bf16)acc[i][j][1],
                       (bf16)acc[i][j][2], (bf16)acc[i][j][3]};
          *(bf16x4*)(vto + ((size_t)(bh * 96 + dhb + lr)) * 1024 + n0) = pk;
        } else if (which == 0) {
          // q pre-scaled by 1/sqrt(dh) so attention skips the S-scale
#pragma unroll
          for (int r = 0; r < 4; r++)
            qo[((size_t)bh * 1024 + n0 + r) * 96 + dhb + lr] =
                (bf16)(acc[i][j][r] * SCALE_);
        } else {
#pragma unroll
          for (int r = 0; r < 4; r++)
            ko[((size_t)bh * 1024 + n0 + r) * 96 + dhb + lr] =
                (bf16)acc[i][j][r];
        }
      } else {
#pragma unroll
        for (int r = 0; r < 4; r++) {
          int row = bm0 + wm + i * 16 + qd * 4 + r;
          int col = bn0 + wn + j * 16 + lr;
          size_t o = (size_t)row * NN + col;
          float v = acc[i][j][r];
          if (EPI == 2) {
            outbs[o] = (bf16)gelu_f(v + bias[col]);
          } else {  // EPI == 5
            outbs[o] = (bf16)v;
          }
        }
      }
    }
  }
}

// -------- fused attention + Wo + bias + residual + LN2, 128 q-rows/block ------
// Main loop = R7 (no setprio — m190 regime: waves barrier-locked). Ps gets an
// XOR swizzle (physcol = col ^ 16*((row>>2)&3)): write banks all-32-distinct
// (was 4-way -> the 3.93M conflicts), reads stay at b128 minimum; layout
// permutation only, numerics unchanged.
// EPILOGUE: this block's 128 q-values form 16 COMPLETE 768-wide operm rows
// (the faithful buggy reshape). So finish the chain here: stage rows to LDS
// in M=16 A-frag layout (stride 784 bf16: 16B-aligned, conflict-free), 288
// MFMA/wave vs fwo fragments (contiguous 1KB L2 reads), + b_o + resid x,
// LN2 inline (16-lane shfl + cross-wave LDS reduce) -> x2, h2.
// Deletes Wo GEMM + ln2_reduce + operm traffic; Wo now pure-fp32 accum.
__global__ __launch_bounds__(256) void attn_kernel(
    const bf16* __restrict__ qb, const bf16* __restrict__ kb,
    const bf16* __restrict__ vtb, const bf16* __restrict__ fwo,
    const float* __restrict__ bo, const float* __restrict__ xres,
    const float* __restrict__ gm, const float* __restrict__ bm,
    bf16* __restrict__ x2o, bf16* __restrict__ h2o) {
  __shared__ __align__(16) bf16 Ks[2][64 * 104];   // [key][dh], pad 104
  __shared__ __align__(16) bf16 Vs[2][96 * 72];    // [dh][key], pad 72
  __shared__ __align__(16) bf16 Ps[128 * 72];      // [qrow][key^swz], pad 72
  int t = threadIdx.x;
  int w = t >> 6, lane = t & 63;
  int qd = lane >> 4, lr = lane & 15;
  int bh = blockIdx.x, nt0 = blockIdx.y * 128;
  int bq = bh >> 3, hh = bh & 7;

  const bf16* kgb = kb + (size_t)bh * 1024 * 96;
  const bf16* vgb = vtb + (size_t)bh * 96 * 1024;

  bf16x8 kreg[3], vreg[3];
#pragma unroll
  for (int it = 0; it < 3; it++) {
    int idx = it * 256 + t;
    kreg[it] = *(const bf16x8*)(kgb + (idx / 12) * 96 + (idx % 12) * 8);
    vreg[it] = *(const bf16x8*)(vgb + (size_t)(idx >> 3) * 1024 + (idx & 7) * 8);
  }

  const bf16* qg = qb + ((size_t)bh * 1024 + nt0 + w * 32) * 96;
  bf16x8 afq[2][3];
#pragma unroll
  for (int i = 0; i < 2; i++)
#pragma unroll
    for (int ks = 0; ks < 3; ks++)
      afq[i][ks] = *(const bf16x8*)(qg + (i * 16 + lr) * 96 + ks * 32 + qd * 8);

  f32x4 oacc[2][6] = {};
  float lst[2][4] = {};

  int cur = 0;
  for (int kt = 0; kt < 16; kt++) {
#pragma unroll
    for (int it = 0; it < 3; it++) {
      int idx = it * 256 + t;
      *(bf16x8*)&Ks[cur][(idx / 12) * 104 + (idx % 12) * 8] = kreg[it];
      *(bf16x8*)&Vs[cur][(idx >> 3) * 72 + (idx & 7) * 8] = vreg[it];
    }
    if (kt < 15) {
      const bf16* kg = kgb + (size_t)(kt + 1) * 64 * 96;
      const bf16* vg = vgb + (kt + 1) * 64;
#pragma unroll
      for (int it = 0; it < 3; it++) {
        int idx = it * 256 + t;
        kreg[it] = *(const bf16x8*)(kg + (idx / 12) * 96 + (idx % 12) * 8);
        vreg[it] =
            *(const bf16x8*)(vg + (size_t)(idx >> 3) * 1024 + (idx & 7) * 8);
      }
    }
    __syncthreads();

    f32x4 sacc[2][4] = {};
#pragma unroll
    for (int ks = 0; ks < 3; ks++) {
      bf16x8 bk[4];
#pragma unroll
      for (int jn = 0; jn < 4; jn++)
        bk[jn] =
            *(const bf16x8*)&Ks[cur][(jn * 16 + lr) * 104 + ks * 32 + qd * 8];
#pragma unroll
      for (int i = 0; i < 2; i++)
#pragma unroll
        for (int jn = 0; jn < 4; jn++)
          sacc[i][jn] = __builtin_amdgcn_mfma_f32_16x16x32_bf16(
              afq[i][ks], bk[jn], sacc[i][jn], 0, 0, 0);
    }

#pragma unroll
    for (int i = 0; i < 2; i++)
#pragma unroll
      for (int jn = 0; jn < 4; jn++)
#pragma unroll
        for (int r = 0; r < 4; r++) {
          float p = __expf(sacc[i][jn][r]);
          lst[i][r] += p;
          // XOR-swizzled column: row's qd spreads writes over all 32 banks
          Ps[(w * 32 + i * 16 + qd * 4 + r) * 72 + ((jn ^ qd) * 16 + lr)] =
              (bf16)p;
        }

#pragma unroll
    for (int ks = 0; ks < 2; ks++) {
      bf16x8 ap[2];
#pragma unroll
      for (int i = 0; i < 2; i++)
        ap[i] = *(const bf16x8*)&Ps[(w * 32 + i * 16 + lr) * 72 +
                                    ((ks * 32 + qd * 8) ^
                                     (((lr >> 2) & 3) * 16))];
#pragma unroll
      for (int jn = 0; jn < 6; jn++) {
        bf16x8 bv =
            *(const bf16x8*)&Vs[cur][(jn * 16 + lr) * 72 + ks * 32 + qd * 8];
#pragma unroll
        for (int i = 0; i < 2; i++)
          oacc[i][jn] = __builtin_amdgcn_mfma_f32_16x16x32_bf16(
              ap[i], bv, oacc[i][jn], 0, 0, 0);
      }
    }
    cur ^= 1;
  }

#pragma unroll
  for (int i = 0; i < 2; i++)
#pragma unroll
    for (int r = 0; r < 4; r++) {
#pragma unroll
      for (int off = 1; off < 16; off <<= 1)
        lst[i][r] += __shfl_xor(lst[i][r], off);
    }

  // ================= fused Wo + bias + residual + LN2 =================
  bf16* Po = (bf16*)&Ks[0][0];          // 16 x 784 bf16 = 25088 B (<= 26624)
  float* red = (float*)&Vs[0][0];       // 16 rows x 4 waves x {s,sq}
  int Rbase = bq * 1024 + hh * 128 + (nt0 >> 3);

  __syncthreads();   // all K/V/P reads done; safe to overwrite Ks
#pragma unroll
  for (int i = 0; i < 2; i++) {
#pragma unroll
    for (int r = 0; r < 4; r++) {
      float inv = 1.0f / lst[i][r];
      int nn = i * 16 + qd * 4 + r;       // n-offset within wave's 32
      int rloc = w * 4 + (nn >> 3);       // block-local operm row 0..15
      int colb = 96 * (nn & 7);
#pragma unroll
      for (int jn = 0; jn < 6; jn++)
        Po[rloc * 784 + colb + jn * 16 + lr] = (bf16)(oacc[i][jn][r] * inv);
    }
  }
  __syncthreads();

  // y[16 x 768] = Po @ w_o ; wave w owns cols [w*192, w*192+192)
  f32x4 ya[12] = {};
#pragma unroll 1
  for (int kc = 0; kc < 24; ++kc) {
    bf16x8 a = *(const bf16x8*)&Po[lr * 784 + kc * 32 + qd * 8];
    const bf16* bp = fwo + ((size_t)(w * 12) * 24 + kc) * 512 + lane * 8;
#pragma unroll
    for (int j = 0; j < 12; ++j)
      ya[j] = __builtin_amdgcn_mfma_f32_16x16x32_bf16(
          a, *(const bf16x8*)(bp + (size_t)j * 12288), ya[j], 0, 0, 0);
  }

  float s4[4] = {}, q4[4] = {};
#pragma unroll
  for (int j = 0; j < 12; ++j) {
    int col = (w * 12 + j) * 16 + lr;
    float bcol = bo[col];
#pragma unroll
    for (int rr = 0; rr < 4; ++rr) {
      size_t R = (size_t)(Rbase + qd * 4 + rr);
      float tv = ya[j][rr] + bcol + xres[R * 768 + col];
      ya[j][rr] = tv;
      s4[rr] += tv;
      q4[rr] += tv * tv;
    }
  }
#pragma unroll
  for (int rr = 0; rr < 4; ++rr) {
#pragma unroll
    for (int off = 1; off < 16; off <<= 1) {
      s4[rr] += __shfl_xor(s4[rr], off);
      q4[rr] += __shfl_xor(q4[rr], off);
    }
  }
  if (lr == 0) {
#pragma unroll
    for (int rr = 0; rr < 4; ++rr) {
      red[(qd * 4 + rr) * 8 + w * 2] = s4[rr];
      red[(qd * 4 + rr) * 8 + w * 2 + 1] = q4[rr];
    }
  }
  __syncthreads();
  float mean[4], rstd[4];
#pragma unroll
  for (int rr = 0; rr < 4; ++rr) {
    float ss = 0.f, qq = 0.f;
#pragma unroll
    for (int wv = 0; wv < 4; ++wv) {
      ss += red[(qd * 4 + rr) * 8 + wv * 2];
      qq += red[(qd * 4 + rr) * 8 + wv * 2 + 1];
    }
    mean[rr] = ss * (1.f / 768.f);
    rstd[rr] = rsqrtf(qq * (1.f / 768.f) - mean[rr] * mean[rr] + 1e-5f);
  }
#pragma unroll
  for (int j = 0; j < 12; ++j) {
    int col = (w * 12 + j) * 16 + lr;
    float gg = gm[col], bb = bm[col];
#pragma unroll
    for (int rr = 0; rr < 4; ++rr) {
      size_t R = (size_t)(Rbase + qd * 4 + rr);
      float tv = ya[j][rr];
      x2o[R * 768 + col] = (bf16)tv;
      h2o[R * 768 + col] = (bf16)((tv - mean[rr]) * rstd[rr] * gg + bb);
    }
  }
}

// ------------------------------------------------------------------------------
extern "C" void kernel_launch(void* const* d_in, const int* in_sizes, int n_in,
                              void* d_out, int out_size, void* d_ws,
                              size_t ws_size, hipStream_t stream) {
  const float* x = (const float*)d_in[0];
  const float* w_qkv = (const float*)d_in[1];
  const float* w_o = (const float*)d_in[2];
  const float* b_o = (const float*)d_in[3];
  const float* w1 = (const float*)d_in[4];
  const float* b1 = (const float*)d_in[5];
  const float* w2 = (const float*)d_in[6];
  const float* b2 = (const float*)d_in[7];
  const float* g1 = (const float*)d_in[8];
  const float* be1 = (const float*)d_in[9];
  const float* gm = (const float*)d_in[10];
  const float* bm = (const float*)d_in[11];
  const float* g3 = (const float*)d_in[12];
  const float* be3 = (const float*)d_in[13];

  char* ws = (char*)d_ws;
  size_t off = 0;
  auto alloc = [&](size_t bytes) {
    char* p = ws + off;
    off += (bytes + 255) & ~(size_t)255;
    return p;
  };
  const size_t SZ_TOK_BF = (size_t)M_TOK * 768 * 2;   // 12.58 MB
  bf16* fqkv = (bf16*)alloc((size_t)2304 * 768 * 2);
  bf16* fwo = (bf16*)alloc((size_t)768 * 768 * 2);
  bf16* fw1 = (bf16*)alloc((size_t)3072 * 768 * 2);
  bf16* fw2 = (bf16*)alloc((size_t)768 * 3072 * 2);
  bf16* hA = (bf16*)alloc(SZ_TOK_BF);   // LN1 out; then h2 (attn-fused LN2)
  bf16* qb = (bf16*)alloc(SZ_TOK_BF);
  bf16* kbuf = (bf16*)alloc(SZ_TOK_BF);
  bf16* vtb = (bf16*)alloc(SZ_TOK_BF);
  bf16* x2 = (bf16*)alloc(SZ_TOK_BF);
  char* G = alloc((size_t)M_TOK * 3072 * 2);
  bf16* h2 = hA;
  bf16* a1 = (bf16*)G;
  bf16* pW2 = hA;  // spans hA+qb (2 x 12.58 MB), live after a1's last read

  make_frags_kernel<<<3456, 256, 0, stream>>>(w_qkv, w_o, w1, w2, fqkv, fwo,
                                              fw1, fw2);

  ln_kernel<<<M_TOK / 4, 256, 0, stream>>>(x, g1, be1, hA);

  // QKV GEMM with fused head-split epilogue (q pre-scaled by 1/sqrt(dh))
  gemm128_kernel<4, 768, 768, 768, 2304><<<dim3(64, 18), 256, 0, stream>>>(
      hA, fqkv, nullptr, nullptr, qb, kbuf, vtb);

  // attention + Wo + bias + residual + LN2 fused -> x2 (resid), h2 (LN2 out)
  attn_kernel<<<dim3(64, 8), 256, 0, stream>>>(qb, kbuf, vtb, fwo, b_o, x, gm,
                                               bm, x2, h2);

  // W1 GEMM: bias + GELU -> bf16 a1
  gemm128_kernel<2, 768, 768, 768, 3072><<<dim3(64, 24), 256, 0, stream>>>(
      h2, fw1, b1, a1, nullptr, nullptr, nullptr);

  // W2 GEMM, split-K=2 (slices of 1536) -> bf16 partials spanning hA+qb
  gemm128_kernel<5, 3072, 3072, 1536, 768><<<dim3(64, 6, 2), 256, 0, stream>>>(
      a1, fw2, nullptr, pW2, nullptr, nullptr, nullptr);

  ln3_reduce_kernel<<<M_TOK / 4, 256, 0, stream>>>(pW2, b2, x2, g3, be3,
                                                   (float*)d_out);
}